// Round 10
// baseline (201.337 us; speedup 1.0000x reference)
//
#include <hip/hip_runtime.h>

#define BATCH 32
#define NOBJ  64
#define PADK  264   // halfs; A-tile row stride 528 B (16B-aligned)

typedef _Float16 f16x2 __attribute__((ext_vector_type(2)));
typedef _Float16 f16x4 __attribute__((ext_vector_type(4)));
typedef _Float16 f16x8 __attribute__((ext_vector_type(8)));
typedef float    f32x4 __attribute__((ext_vector_type(4)));
typedef float    f32x16 __attribute__((ext_vector_type(16)));

#define MFMA32(a, b, c) __builtin_amdgcn_mfma_f32_32x32x16_f16((a), (b), (c), 0, 0, 0)

// ---------------------------------------------------------------------------
// Layer-0 split: pair = [x_j-part (65) | x_i-part (129)].
// x_i-part is constant over the 64 j-rows -> precompute
//   ci[b][i][n] = sum_q x_aux[b][i][q] * g1w[65+q][n] + i * g1w[193][n]  (fp32)
// and run layer-0 MFMA with K=80, acc initialized from ci. Exact arithmetic.
//
// Activation LDS layout (layers >= 1): physical col p = 64*nq + 2*c + ns
// holds logical col n = 64*nq + 32*ns + c. Epilogue writes f16x2.
// Next layer's weight k-order: klog(p) = 64*(p>>6) + 32*(p&1) + ((p&63)>>1).
//
// Dispatch plan (2 total):
//   prep_all (544 blocks): blk<32 -> weight repack + zero xg/cnt;
//                          blk>=32 -> ci precompute.
//   g_mlp_pool (1024 blocks): fused g-MLP + pool; the last block of each
//     batch (per-batch atomic counter) runs the f-MLP for that batch.
// ---------------------------------------------------------------------------

// ---------------------------------------------------------------------------
// Kernel 0: prep_all.
// blk < 32: repack g-weights to f16 MFMA B-fragment order:
//   wtf[l][ngrp=8][kk=16][lane=64][j=8] = W_l[klog][nlog]
//   nlog = ngrp*32 + (lane&31), kphys = kk*16 + (lane>>5)*8 + j
//   l==0 (K=80): klog = kp for kp<=64 (x_j feats + coord j), else zero.
//   l>=1: klog = 64*(kp>>6) + 32*(kp&1) + ((kp&63)>>1)  (2-col interleave).
//   Also zeroes xg (32x256) and cnt (32).
// blk >= 32: ci precompute, block -> (b, group of 4 i), thread t = col n.
// ---------------------------------------------------------------------------
__global__ __launch_bounds__(256) void prep_all(
    const float* __restrict__ x_aux,
    const float* __restrict__ g1w, const float* __restrict__ g2w,
    const float* __restrict__ g3w, const float* __restrict__ g4w,
    _Float16* __restrict__ wtf, float* __restrict__ xg,
    float* __restrict__ ci, int* __restrict__ cnt) {
  __shared__ _Float16 tile[256][33];   // weight path (aliased by ci path)
  const int blk = blockIdx.x;
  const int t = threadIdx.x;

  if (blk < 32) {
    // ---- weight repack ----
    xg[blk * 256 + t] = 0.0f;
    if (blk == 0 && t < 32) cnt[t] = 0;

    const int l  = blk >> 3;
    const int nt = blk & 7;
    const float* src = (l == 0) ? g1w : (l == 1) ? g2w : (l == 2) ? g3w : g4w;

    const int nn = t & 31, kb = t >> 5;   // 8 kphys-rows per pass
#pragma unroll 4
    for (int pass = 0; pass < 32; ++pass) {
      int kp = pass * 8 + kb;             // physical k
      int kl;                             // logical k in W_l
      if (l == 0) {
        kl = (kp <= 64) ? kp : -1;
      } else {
        kl = 64 * (kp >> 6) + 32 * (kp & 1) + ((kp & 63) >> 1);
      }
      float v = (kl >= 0) ? src[(size_t)kl * 256 + nt * 32 + nn] : 0.0f;
      tile[kp][nn] = (_Float16)v;
    }
    __syncthreads();

    const int lane = t & 63;
    const int nfrag = lane & 31;
    const int kbase = (lane >> 5) * 8;
    _Float16* dst = wtf + ((size_t)(l * 8 + nt) * 16) * 512;
#pragma unroll
    for (int q = 0; q < 4; ++q) {
      int kk = (t >> 6) + 4 * q;
      f16x8 fr;
#pragma unroll
      for (int j = 0; j < 8; ++j)
        fr[j] = tile[kk * 16 + kbase + j][nfrag];
      *(f16x8*)(dst + (size_t)kk * 512 + lane * 8) = fr;
    }
  } else {
    // ---- ci precompute ----
    float* xs = (float*)&tile[0][0];     // [4][128]
    const int blkc = blk - 32;           // 512 = 32 b x 16 groups
    const int b  = blkc >> 4;
    const int i0 = (blkc & 15) * 4;

#pragma unroll
    for (int u = 0; u < 2; ++u) {
      int idx = u * 256 + t;             // 0..511
      int j = idx >> 7, k = idx & 127;
      xs[j * 128 + k] = x_aux[((size_t)(b * NOBJ + i0 + j)) * 128 + k];
    }
    __syncthreads();

    float c0 = 0.f, c1 = 0.f, c2 = 0.f, c3 = 0.f;
#pragma unroll 8
    for (int k = 0; k < 128; ++k) {
      float w = g1w[(size_t)(65 + k) * 256 + t];
      c0 += xs[k] * w;       c1 += xs[128 + k] * w;
      c2 += xs[256 + k] * w; c3 += xs[384 + k] * w;
    }
    float wc = g1w[(size_t)193 * 256 + t];
    c0 += (float)(i0 + 0) * wc;
    c1 += (float)(i0 + 1) * wc;
    c2 += (float)(i0 + 2) * wc;
    c3 += (float)(i0 + 3) * wc;
    ci[((size_t)(b * NOBJ + i0 + 0)) * 256 + t] = c0;
    ci[((size_t)(b * NOBJ + i0 + 1)) * 256 + t] = c1;
    ci[((size_t)(b * NOBJ + i0 + 2)) * 256 + t] = c2;
    ci[((size_t)(b * NOBJ + i0 + 3)) * 256 + t] = c3;
  }
}

// ---------------------------------------------------------------------------
// One layer GEMM for a wave: Mt=4 M-tiles x Nt=2 N-groups, STEPS k-steps.
// Whole-layer B preloaded into registers. acc[idx = m*2 + ns].
// ---------------------------------------------------------------------------
template <int STEPS>
__device__ __forceinline__ void do_layer(
    const _Float16* __restrict__ bp0, const _Float16* __restrict__ bp1,
    const _Float16* __restrict__ arow, f32x16 acc[8]) {
  f16x8 b0[STEPS], b1[STEPS];
#pragma unroll
  for (int kk = 0; kk < STEPS; ++kk) {
    b0[kk] = *(const f16x8*)(bp0 + kk * 512);
    b1[kk] = *(const f16x8*)(bp1 + kk * 512);
  }
#pragma unroll
  for (int kk = 0; kk < STEPS; ++kk) {
#pragma unroll
    for (int m = 0; m < 4; ++m) {
      f16x8 a = *(const f16x8*)(arow + (size_t)m * 32 * PADK + kk * 16);
      acc[m * 2]     = MFMA32(a, b0[kk], acc[m * 2]);
      acc[m * 2 + 1] = MFMA32(a, b1[kk], acc[m * 2 + 1]);
    }
  }
}

// ---------------------------------------------------------------------------
// Kernel 1: fused g-MLP (4 layers) + sum-pool for TWO i's per block, plus
// per-batch f-MLP in the last-finishing block of each batch.
// Block = 256 thr (4 waves). M=128 (2 i's x 64 j), N=256.
// Wave w = nq: Mt=4 x Nt=2 (N-groups 2nq, 2nq+1); dup=1 B (validated).
// Layer 0: K=80 (5 steps), acc init from ci. Layers 1-3: K=256 (16 steps).
// ---------------------------------------------------------------------------
__global__ __launch_bounds__(256, 2) void g_mlp_pool(
    const float* __restrict__ x_aux,          // [B, 64, 128] fp32
    const _Float16* __restrict__ wtf,         // fragment-ordered, 512 KB
    const float* __restrict__ ci,             // [B*64][256] fp32
    const float* __restrict__ g1b, const float* __restrict__ g2b,
    const float* __restrict__ g3b, const float* __restrict__ g4b,
    float* __restrict__ xg,                   // [B][256] fp32 (pre-zeroed)
    int* __restrict__ cnt,                    // [B] (pre-zeroed)
    const float* __restrict__ f1w, const float* __restrict__ f1b,
    const float* __restrict__ f2w, const float* __restrict__ f2b,
    const float* __restrict__ f3w, const float* __restrict__ f3b,
    float* __restrict__ out) {                // [B][256] fp32
  __shared__ _Float16 As[128][PADK];          // 67.6 KB -> 2 blocks/CU
  __shared__ int is_last;

  const int b  = blockIdx.x >> 5;
  const int i0 = (blockIdx.x & 31) * 2;
  const int t  = threadIdx.x;

  // ---- build layer-0 input tile: only the x_j-part (cols 0..79) ----
  {
    const float* xb = x_aux + (size_t)b * NOBJ * 128;
    const int c4 = t & 15, r0 = t >> 4;       // cols [0,64): 16 rows/pass
#pragma unroll
    for (int it = 0; it < 8; ++it) {
      int r = it * 16 + r0;
      f32x4 v = *(const f32x4*)(xb + (size_t)(r & 63) * 128 + c4 * 4);
      f16x4 hh = {(_Float16)v[0], (_Float16)v[1], (_Float16)v[2], (_Float16)v[3]};
      *(f16x4*)&As[r][c4 * 4] = hh;
    }
    if (t < 128) {                            // cols [64,80): coord j + zeros
      f16x8 z1 = {};
      z1[0] = (_Float16)(t & 63);             // coord j
      *(f16x8*)&As[t][64] = z1;
      f16x8 z = {};
      *(f16x8*)&As[t][72] = z;
    }
  }
  __syncthreads();

  const int lane = t & 63;
  const int nq   = t >> 6;          // 0..3 -> N-pair (groups 2nq, 2nq+1)
  const int c31  = lane & 31;
  const int h    = lane >> 5;       // 0/1
  const int n0   = nq * 64;
  const float* gb[4] = {g1b, g2b, g3b, g4b};

  // per-lane layer-0 constants (broadcast over the 16 rows of each acc reg)
  const float* cb = ci + (size_t)(b * NOBJ + i0) * 256;
  const float ci_v[2][2] = {{cb[n0 + c31], cb[n0 + 32 + c31]},
                            {cb[256 + n0 + c31], cb[256 + n0 + 32 + c31]}};

  for (int layer = 0; layer < 4; ++layer) {
    const float bv0 = gb[layer][n0 + c31];
    const float bv1 = gb[layer][n0 + 32 + c31];

    f32x16 acc[8];   // [m*2 + ns]

    const _Float16* bp0 =
        wtf + ((size_t)(layer * 8 + nq * 2) * 16) * 512 + lane * 8;
    const _Float16* bp1 = bp0 + 16 * 512;
    const _Float16* arow = &As[c31][h * 8];

    if (layer == 0) {
      // rows 0..63 (m=0,1) belong to i0; rows 64..127 (m=2,3) to i0+1
#pragma unroll
      for (int m = 0; m < 4; ++m)
#pragma unroll
        for (int ns = 0; ns < 2; ++ns)
#pragma unroll
          for (int reg = 0; reg < 16; ++reg)
            acc[m * 2 + ns][reg] = ci_v[m >> 1][ns];
      do_layer<5>(bp0, bp1, arow, acc);
    } else {
#pragma unroll
      for (int x = 0; x < 8; ++x) acc[x] = (f32x16){};
      do_layer<16>(bp0, bp1, arow, acc);
    }

    if (layer < 3) {
      __syncthreads();   // all waves done reading As
      // C/D layout: col = lane&31, row = (reg&3) + 8*(reg>>2) + 4*h.
      // Pack both N-streams as f16x2 at phys col 64*nq + 2*c.
#pragma unroll
      for (int m = 0; m < 4; ++m)
#pragma unroll
        for (int g = 0; g < 4; ++g)
#pragma unroll
          for (int r = 0; r < 4; ++r) {
            const int row = m * 32 + g * 8 + h * 4 + r;
            const int reg = g * 4 + r;
            f16x2 pk = {(_Float16)fmaxf(acc[m * 2][reg] + bv0, 0.f),
                        (_Float16)fmaxf(acc[m * 2 + 1][reg] + bv1, 0.f)};
            *(f16x2*)&As[row][n0 + 2 * c31] = pk;
          }
      __syncthreads();
    } else {
      // layer 4: bias + relu + pool over all 128 rows (both i's)
      float s0 = 0.f, s1 = 0.f;
#pragma unroll
      for (int m = 0; m < 4; ++m)
#pragma unroll
        for (int reg = 0; reg < 16; ++reg) {
          s0 += fmaxf(acc[m * 2][reg] + bv0, 0.f);
          s1 += fmaxf(acc[m * 2 + 1][reg] + bv1, 0.f);
        }
      s0 += __shfl_xor(s0, 32, 64);   // combine h=0/h=1 row halves
      s1 += __shfl_xor(s1, 32, 64);
      if (h == 0) {
        atomicAdd(&xg[b * 256 + n0 + c31], s0);
        atomicAdd(&xg[b * 256 + n0 + 32 + c31], s1);
      }
    }
  }

  // ---- per-batch completion; last block of batch b runs the f-MLP ----
  __syncthreads();                 // drains vmcnt -> xg atomics performed
  if (t == 0) {
    __threadfence();
    is_last = (atomicAdd(&cnt[b], 1) == 31) ? 1 : 0;
  }
  __syncthreads();
  if (!is_last) return;

  // f-MLP for batch b: thread t owns output column t. fp32 math.
  float* fx = (float*)&As[0][0];   // reuse LDS: xs[256], ys[256]
  float* fy = fx + 256;

  __threadfence();
  fx[t] = __hip_atomic_load(&xg[b * 256 + t], __ATOMIC_RELAXED,
                            __HIP_MEMORY_SCOPE_AGENT);
  __syncthreads();

  float a = f1b[t];
#pragma unroll 16
  for (int k = 0; k < 256; ++k) a += fx[k] * f1w[(size_t)k * 256 + t];
  fy[t] = fmaxf(a, 0.f);
  __syncthreads();

  a = f2b[t];
#pragma unroll 16
  for (int k = 0; k < 256; ++k) a += fy[k] * f2w[(size_t)k * 256 + t];
  fx[t] = fmaxf(a, 0.f);
  __syncthreads();

  a = f3b[t];
#pragma unroll 16
  for (int k = 0; k < 256; ++k) a += fx[k] * f3w[(size_t)k * 256 + t];
  out[b * 256 + t] = a;
}

// ---------------------------------------------------------------------------
extern "C" void kernel_launch(void* const* d_in, const int* in_sizes, int n_in,
                              void* d_out, int out_size, void* d_ws, size_t ws_size,
                              hipStream_t stream) {
  const float* x_aux = (const float*)d_in[0];
  const float* g1w = (const float*)d_in[1];
  const float* g1b = (const float*)d_in[2];
  const float* g2w = (const float*)d_in[3];
  const float* g2b = (const float*)d_in[4];
  const float* g3w = (const float*)d_in[5];
  const float* g3b = (const float*)d_in[6];
  const float* g4w = (const float*)d_in[7];
  const float* g4b = (const float*)d_in[8];
  const float* f1w = (const float*)d_in[9];
  const float* f1b = (const float*)d_in[10];
  const float* f2w = (const float*)d_in[11];
  const float* f2b = (const float*)d_in[12];
  const float* f3w = (const float*)d_in[13];
  const float* f3b = (const float*)d_in[14];
  float* out = (float*)d_out;

  _Float16* wtf = (_Float16*)d_ws;                                  // 512 KB
  float* xg = (float*)((char*)d_ws + 512u * 1024u);                 // 32 KB
  float* ci = (float*)((char*)d_ws + 512u * 1024u + 32u * 1024u);   // 2 MB
  int* cnt  = (int*)((char*)d_ws + 512u * 1024u + 32u * 1024u
                     + 2048u * 1024u);                              // 128 B

  hipLaunchKernelGGL(prep_all, dim3(544), dim3(256), 0, stream,
                     x_aux, g1w, g2w, g3w, g4w, wtf, xg, ci, cnt);
  hipLaunchKernelGGL(g_mlp_pool, dim3(BATCH * 32), dim3(256), 0, stream,
                     x_aux, wtf, ci, g1b, g2b, g3b, g4b, xg, cnt,
                     f1w, f1b, f2w, f2b, f3w, f3b, out);
}

// Round 11
// 147.647 us; speedup vs baseline: 1.3636x; 1.3636x over previous
//
#include <hip/hip_runtime.h>

#define BATCH 32
#define NOBJ  64
#define PADK  264   // halfs; A-tile row stride 528 B (16B-aligned)

typedef _Float16 f16x2 __attribute__((ext_vector_type(2)));
typedef _Float16 f16x4 __attribute__((ext_vector_type(4)));
typedef _Float16 f16x8 __attribute__((ext_vector_type(8)));
typedef float    f32x4 __attribute__((ext_vector_type(4)));
typedef float    f32x16 __attribute__((ext_vector_type(16)));

#define MFMA32(a, b, c) __builtin_amdgcn_mfma_f32_32x32x16_f16((a), (b), (c), 0, 0, 0)

// ---------------------------------------------------------------------------
// Layer-0 is removed from the MFMA loop entirely (exact algebra):
//   h1[b][(i,j)][n] = relu( h0j[b][j][n] + cib[b][i][n] )
//   h0j = x_j·W0[0:64] + j·W0[64]          (per-batch, shared by all i)
//   cib = x_i·W0[65:193] + i·W0[193] + b1  (per-(b,i))
// Both fp32, computed in prep_all. g_mlp builds act1 directly and runs
// layers 1-3 (K=256, 16 steps each).
//
// Activation LDS layout after layer-1/2 epilogues: physical col
// p = 64*nq + 2*c + ns holds logical col n = 64*nq + 32*ns + c (f16x2 pack).
// Layer-2/3 weight k-order: klog(p) = 64*(p>>6) + 32*(p&1) + ((p&63)>>1).
// Layer-1 weights use identity k-order (act1 is built in plain layout).
//
// Dispatches (3): prep_all (800 blocks), g_mlp_pool (1024), f_mlp (32).
// NO device-scope fences anywhere (r10 lesson: __threadfence = L2 flush).
// ---------------------------------------------------------------------------

// ---------------------------------------------------------------------------
// Kernel 0: prep_all.
// blk 0..31  : zero xg; repack weights l=blk>>3 in MFMA B-fragment order
//              (skip l==0 -- unused):
//              wtf[l][ngrp=8][kk=16][lane=64][j=8] = W_l[klog][nlog]
//              nlog = ngrp*32+(lane&31), kphys = kk*16+(lane>>5)*8+j
//              l==1: klog = kphys; l>=2: 2-col interleave mapping.
// blk 32..543: cib (per-(b, 4 i's)); thread t = col n.
// blk 544..799: h0j (per-(b, 8 j's)); thread t = col n.
// ---------------------------------------------------------------------------
__global__ __launch_bounds__(256) void prep_all(
    const float* __restrict__ x_aux,
    const float* __restrict__ g1w, const float* __restrict__ g1b,
    const float* __restrict__ g2w, const float* __restrict__ g3w,
    const float* __restrict__ g4w,
    _Float16* __restrict__ wtf, float* __restrict__ xg,
    float* __restrict__ cib, float* __restrict__ h0j) {
  __shared__ _Float16 tile[256][33];
  const int blk = blockIdx.x;
  const int t = threadIdx.x;

  if (blk < 32) {
    xg[blk * 256 + t] = 0.0f;
    const int l = blk >> 3;
    if (l == 0) return;                 // layer-0 weights not needed
    const int nt = blk & 7;
    const float* src = (l == 1) ? g2w : (l == 2) ? g3w : g4w;

    const int nn = t & 31, kb = t >> 5;
#pragma unroll 4
    for (int pass = 0; pass < 32; ++pass) {
      int kp = pass * 8 + kb;
      int kl = (l == 1) ? kp
                        : 64 * (kp >> 6) + 32 * (kp & 1) + ((kp & 63) >> 1);
      tile[kp][nn] = (_Float16)src[(size_t)kl * 256 + nt * 32 + nn];
    }
    __syncthreads();

    const int lane = t & 63;
    const int nfrag = lane & 31;
    const int kbase = (lane >> 5) * 8;
    _Float16* dst = wtf + ((size_t)(l * 8 + nt) * 16) * 512;
#pragma unroll
    for (int q = 0; q < 4; ++q) {
      int kk = (t >> 6) + 4 * q;
      f16x8 fr;
#pragma unroll
      for (int j = 0; j < 8; ++j)
        fr[j] = tile[kk * 16 + kbase + j][nfrag];
      *(f16x8*)(dst + (size_t)kk * 512 + lane * 8) = fr;
    }
  } else if (blk < 544) {
    // ---- cib = x_i . W0[65:193] + i*W0[193] + b1  (fp32) ----
    float* xs = (float*)&tile[0][0];     // [4][128]
    const int blkc = blk - 32;           // 512 = 32 b x 16 groups
    const int b  = blkc >> 4;
    const int i0 = (blkc & 15) * 4;

#pragma unroll
    for (int u = 0; u < 2; ++u) {
      int idx = u * 256 + t;
      int j = idx >> 7, k = idx & 127;
      xs[j * 128 + k] = x_aux[((size_t)(b * NOBJ + i0 + j)) * 128 + k];
    }
    __syncthreads();

    float c0 = 0.f, c1 = 0.f, c2 = 0.f, c3 = 0.f;
#pragma unroll 8
    for (int k = 0; k < 128; ++k) {
      float w = g1w[(size_t)(65 + k) * 256 + t];
      c0 += xs[k] * w;       c1 += xs[128 + k] * w;
      c2 += xs[256 + k] * w; c3 += xs[384 + k] * w;
    }
    float wc = g1w[(size_t)193 * 256 + t];
    float bb = g1b[t];
    c0 += (float)(i0 + 0) * wc + bb;
    c1 += (float)(i0 + 1) * wc + bb;
    c2 += (float)(i0 + 2) * wc + bb;
    c3 += (float)(i0 + 3) * wc + bb;
    cib[((size_t)(b * NOBJ + i0 + 0)) * 256 + t] = c0;
    cib[((size_t)(b * NOBJ + i0 + 1)) * 256 + t] = c1;
    cib[((size_t)(b * NOBJ + i0 + 2)) * 256 + t] = c2;
    cib[((size_t)(b * NOBJ + i0 + 3)) * 256 + t] = c3;
  } else {
    // ---- h0j = x_j . W0[0:64] + j*W0[64]  (fp32, no bias) ----
    float* xs = (float*)&tile[0][0];     // [8][65]
    const int blk2 = blk - 544;          // 256 = 32 b x 8 jgroups
    const int b  = blk2 >> 3;
    const int j0 = (blk2 & 7) * 8;

#pragma unroll
    for (int u = 0; u < 2; ++u) {
      int idx = u * 256 + t;             // 0..511
      int jj = idx >> 6, k = idx & 63;
      xs[jj * 65 + k] = x_aux[((size_t)(b * NOBJ + j0 + jj)) * 128 + k];
    }
    if (t < 8) xs[t * 65 + 64] = (float)(j0 + t);   // coord j
    __syncthreads();

    float acc[8] = {};
#pragma unroll 5
    for (int k = 0; k < 65; ++k) {
      float w = g1w[(size_t)k * 256 + t];
#pragma unroll
      for (int jj = 0; jj < 8; ++jj) acc[jj] += xs[jj * 65 + k] * w;
    }
#pragma unroll
    for (int jj = 0; jj < 8; ++jj)
      h0j[((size_t)(b * NOBJ + j0 + jj)) * 256 + t] = acc[jj];
  }
}

// ---------------------------------------------------------------------------
// One layer GEMM for a wave: Mt=4 M-tiles x Nt=2 N-groups, 16 k-steps.
// Whole-layer B preloaded into registers. acc[idx = m*2 + ns].
// ---------------------------------------------------------------------------
__device__ __forceinline__ void do_layer16(
    const _Float16* __restrict__ bp0, const _Float16* __restrict__ bp1,
    const _Float16* __restrict__ arow, f32x16 acc[8]) {
  f16x8 b0[16], b1[16];
#pragma unroll
  for (int kk = 0; kk < 16; ++kk) {
    b0[kk] = *(const f16x8*)(bp0 + kk * 512);
    b1[kk] = *(const f16x8*)(bp1 + kk * 512);
  }
#pragma unroll
  for (int kk = 0; kk < 16; ++kk) {
#pragma unroll
    for (int m = 0; m < 4; ++m) {
      f16x8 a = *(const f16x8*)(arow + (size_t)m * 32 * PADK + kk * 16);
      acc[m * 2]     = MFMA32(a, b0[kk], acc[m * 2]);
      acc[m * 2 + 1] = MFMA32(a, b1[kk], acc[m * 2 + 1]);
    }
  }
}

// ---------------------------------------------------------------------------
// Kernel 1: fused g-MLP layers 1-3 + sum-pool for TWO i's per block.
// Block = 256 thr (4 waves). M=128 (2 i's x 64 j), N=256, K=256.
// Tile build: act1[m][n] = relu(h0j[j] + cib[i]) -- coalesced (1 KB row
// per wave instruction), h0j row read once for both i-halves.
// Wave w = nq: Mt=4 x Nt=2 (N-groups 2nq, 2nq+1); dup=1 B (validated).
// ---------------------------------------------------------------------------
__global__ __launch_bounds__(256, 2) void g_mlp_pool(
    const float* __restrict__ h0j,            // [B*64][256] fp32
    const float* __restrict__ cib,            // [B*64][256] fp32
    const _Float16* __restrict__ wtf,         // fragment-ordered
    const float* __restrict__ g2b, const float* __restrict__ g3b,
    const float* __restrict__ g4b,
    float* __restrict__ xg) {                 // [B][256] fp32 (pre-zeroed)
  __shared__ _Float16 As[128][PADK];          // 67.6 KB -> 2 blocks/CU

  const int b  = blockIdx.x >> 5;
  const int i0 = (blockIdx.x & 31) * 2;
  const int t  = threadIdx.x;
  const int lane = t & 63;
  const int wv   = t >> 6;

  // ---- build act1 tile: rows j and 64+j share the same h0j row ----
  {
    const int c = lane * 4;                   // this lane's 4 cols
    const float* hb = h0j + (size_t)(b * NOBJ) * 256 + c;
    const float* c0p = cib + (size_t)(b * NOBJ + i0) * 256 + c;
    f32x4 cv0 = *(const f32x4*)c0p;
    f32x4 cv1 = *(const f32x4*)(c0p + 256);
#pragma unroll
    for (int it = 0; it < 16; ++it) {
      int j = it * 4 + wv;
      f32x4 hv = *(const f32x4*)(hb + (size_t)j * 256);
      f16x4 p0, p1;
#pragma unroll
      for (int q = 0; q < 4; ++q) {
        p0[q] = (_Float16)fmaxf(hv[q] + cv0[q], 0.f);
        p1[q] = (_Float16)fmaxf(hv[q] + cv1[q], 0.f);
      }
      *(f16x4*)&As[j][c]      = p0;
      *(f16x4*)&As[64 + j][c] = p1;
    }
  }
  __syncthreads();

  const int nq   = wv;              // 0..3 -> N-pair (groups 2nq, 2nq+1)
  const int c31  = lane & 31;
  const int h    = lane >> 5;       // 0/1
  const int n0   = nq * 64;
  const float* gb[4] = {nullptr, g2b, g3b, g4b};

  for (int layer = 1; layer < 4; ++layer) {
    const float bv0 = gb[layer][n0 + c31];
    const float bv1 = gb[layer][n0 + 32 + c31];

    f32x16 acc[8];   // [m*2 + ns]
#pragma unroll
    for (int x = 0; x < 8; ++x) acc[x] = (f32x16){};

    const _Float16* bp0 =
        wtf + ((size_t)(layer * 8 + nq * 2) * 16) * 512 + lane * 8;
    const _Float16* bp1 = bp0 + 16 * 512;
    const _Float16* arow = &As[c31][h * 8];

    do_layer16(bp0, bp1, arow, acc);

    if (layer < 3) {
      __syncthreads();   // all waves done reading As
      // C/D layout: col = lane&31, row = (reg&3) + 8*(reg>>2) + 4*h.
      // Pack both N-streams as f16x2 at phys col 64*nq + 2*c.
#pragma unroll
      for (int m = 0; m < 4; ++m)
#pragma unroll
        for (int g = 0; g < 4; ++g)
#pragma unroll
          for (int r = 0; r < 4; ++r) {
            const int row = m * 32 + g * 8 + h * 4 + r;
            const int reg = g * 4 + r;
            f16x2 pk = {(_Float16)fmaxf(acc[m * 2][reg] + bv0, 0.f),
                        (_Float16)fmaxf(acc[m * 2 + 1][reg] + bv1, 0.f)};
            *(f16x2*)&As[row][n0 + 2 * c31] = pk;
          }
      __syncthreads();
    } else {
      // layer 4: bias + relu + pool over all 128 rows (both i's)
      float s0 = 0.f, s1 = 0.f;
#pragma unroll
      for (int m = 0; m < 4; ++m)
#pragma unroll
        for (int reg = 0; reg < 16; ++reg) {
          s0 += fmaxf(acc[m * 2][reg] + bv0, 0.f);
          s1 += fmaxf(acc[m * 2 + 1][reg] + bv1, 0.f);
        }
      s0 += __shfl_xor(s0, 32, 64);   // combine h=0/h=1 row halves
      s1 += __shfl_xor(s1, 32, 64);
      if (h == 0) {
        atomicAdd(&xg[b * 256 + n0 + c31], s0);
        atomicAdd(&xg[b * 256 + n0 + 32 + c31], s1);
      }
    }
  }
}

// ---------------------------------------------------------------------------
// Kernel 2: f-MLP. One block per batch, 1024 threads: n = t&255 owns column,
// kc = t>>8 owns a 64-wide k-chunk; LDS reduce the 4 partials per column.
// ---------------------------------------------------------------------------
__global__ __launch_bounds__(1024) void f_mlp(
    const float* __restrict__ xg,
    const float* __restrict__ f1w, const float* __restrict__ f1b,
    const float* __restrict__ f2w, const float* __restrict__ f2b,
    const float* __restrict__ f3w, const float* __restrict__ f3b,
    float* __restrict__ out) {
  __shared__ float xs[256], ys[256], ps[4][256];
  const int b = blockIdx.x;
  const int t = threadIdx.x;
  const int n = t & 255;
  const int kc = t >> 8;

  if (t < 256) xs[t] = xg[b * 256 + t];
  __syncthreads();

  float p = 0.f;
#pragma unroll 8
  for (int k0 = 0; k0 < 64; ++k0) {
    int k = kc * 64 + k0;
    p += xs[k] * f1w[k * 256 + n];
  }
  ps[kc][n] = p;
  __syncthreads();
  if (t < 256)
    ys[t] = fmaxf(f1b[t] + ps[0][t] + ps[1][t] + ps[2][t] + ps[3][t], 0.f);
  __syncthreads();

  p = 0.f;
#pragma unroll 8
  for (int k0 = 0; k0 < 64; ++k0) {
    int k = kc * 64 + k0;
    p += ys[k] * f2w[k * 256 + n];
  }
  ps[kc][n] = p;
  __syncthreads();
  if (t < 256)
    xs[t] = fmaxf(f2b[t] + ps[0][t] + ps[1][t] + ps[2][t] + ps[3][t], 0.f);
  __syncthreads();

  p = 0.f;
#pragma unroll 8
  for (int k0 = 0; k0 < 64; ++k0) {
    int k = kc * 64 + k0;
    p += xs[k] * f3w[k * 256 + n];
  }
  ps[kc][n] = p;
  __syncthreads();
  if (t < 256)
    out[b * 256 + t] = f3b[t] + ps[0][t] + ps[1][t] + ps[2][t] + ps[3][t];
}

// ---------------------------------------------------------------------------
extern "C" void kernel_launch(void* const* d_in, const int* in_sizes, int n_in,
                              void* d_out, int out_size, void* d_ws, size_t ws_size,
                              hipStream_t stream) {
  const float* x_aux = (const float*)d_in[0];
  const float* g1w = (const float*)d_in[1];
  const float* g1b = (const float*)d_in[2];
  const float* g2w = (const float*)d_in[3];
  const float* g2b = (const float*)d_in[4];
  const float* g3w = (const float*)d_in[5];
  const float* g3b = (const float*)d_in[6];
  const float* g4w = (const float*)d_in[7];
  const float* g4b = (const float*)d_in[8];
  const float* f1w = (const float*)d_in[9];
  const float* f1b = (const float*)d_in[10];
  const float* f2w = (const float*)d_in[11];
  const float* f2b = (const float*)d_in[12];
  const float* f3w = (const float*)d_in[13];
  const float* f3b = (const float*)d_in[14];
  float* out = (float*)d_out;

  _Float16* wtf = (_Float16*)d_ws;                                  // 512 KB
  float* xg  = (float*)((char*)d_ws + 512u * 1024u);                // 32 KB
  float* cib = (float*)((char*)d_ws + 544u * 1024u);                // 2 MB
  float* h0j = (float*)((char*)d_ws + 544u * 1024u + 2048u * 1024u);// 2 MB

  hipLaunchKernelGGL(prep_all, dim3(800), dim3(256), 0, stream,
                     x_aux, g1w, g1b, g2w, g3w, g4w, wtf, xg, cib, h0j);
  hipLaunchKernelGGL(g_mlp_pool, dim3(BATCH * 32), dim3(256), 0, stream,
                     h0j, cib, wtf, g2b, g3b, g4b, xg);
  hipLaunchKernelGGL(f_mlp, dim3(BATCH), dim3(1024), 0, stream,
                     xg, f1w, f1b, f2w, f2b, f3w, f3b, out);
}

// Round 13
// 146.949 us; speedup vs baseline: 1.3701x; 1.0048x over previous
//
#include <hip/hip_runtime.h>

#define BATCH 32
#define NOBJ  64
#define PADK  264   // halfs; A-tile row stride 528 B (16B-aligned)

typedef _Float16 f16x2 __attribute__((ext_vector_type(2)));
typedef __fp16   h16x2 __attribute__((ext_vector_type(2)));
typedef _Float16 f16x4 __attribute__((ext_vector_type(4)));
typedef _Float16 f16x8 __attribute__((ext_vector_type(8)));
typedef float    f32x4 __attribute__((ext_vector_type(4)));
typedef float    f32x16 __attribute__((ext_vector_type(16)));

#define MFMA32(a, b, c) __builtin_amdgcn_mfma_f32_32x32x16_f16((a), (b), (c), 0, 0, 0)

// ---------------------------------------------------------------------------
// Layer-0 is removed from the MFMA loop entirely (exact algebra):
//   h1[b][(i,j)][n] = relu( h0j[b][j][n] + cib[b][i][n] )
//   h0j = x_j·W0[0:64] + j·W0[64]          (per-batch, shared by all i)
//   cib = x_i·W0[65:193] + i·W0[193] + b1  (per-(b,i))
// Both fp32, computed in prep_all. g_mlp builds act1 directly and runs
// layers 1-3 (K=256, 16 steps each).
//
// Activation LDS layout after layer-1/2 epilogues: physical col
// p = 64*nq + 2*c + ns holds logical col n = 64*nq + 32*ns + c (f16x2 pack).
// Layer-2/3 weight k-order: klog(p) = 64*(p>>6) + 32*(p&1) + ((p&63)>>1).
// Layer-1 weights use identity k-order (act1 is built in plain layout).
//
// Dispatches (3): prep_all (800 blocks), g_mlp_pool (1024), f_mlp (32).
// NO device-scope fences anywhere (r10 lesson: __threadfence = L2 flush).
// ---------------------------------------------------------------------------

// ---------------------------------------------------------------------------
// Kernel 0: prep_all.
// blk 0..31  : zero xg; repack weights l=blk>>3 in MFMA B-fragment order
//              (skip l==0 -- unused):
//              wtf[l][ngrp=8][kk=16][lane=64][j=8] = W_l[klog][nlog]
//              nlog = ngrp*32+(lane&31), kphys = kk*16+(lane>>5)*8+j
//              l==1: klog = kphys; l>=2: 2-col interleave mapping.
// blk 32..543: cib (per-(b, 4 i's)); thread t = col n.
// blk 544..799: h0j (per-(b, 8 j's)); thread t = col n.
// ---------------------------------------------------------------------------
__global__ __launch_bounds__(256) void prep_all(
    const float* __restrict__ x_aux,
    const float* __restrict__ g1w, const float* __restrict__ g1b,
    const float* __restrict__ g2w, const float* __restrict__ g3w,
    const float* __restrict__ g4w,
    _Float16* __restrict__ wtf, float* __restrict__ xg,
    float* __restrict__ cib, float* __restrict__ h0j) {
  __shared__ _Float16 tile[256][33];
  const int blk = blockIdx.x;
  const int t = threadIdx.x;

  if (blk < 32) {
    xg[blk * 256 + t] = 0.0f;
    const int l = blk >> 3;
    if (l == 0) return;                 // layer-0 weights not needed
    const int nt = blk & 7;
    const float* src = (l == 1) ? g2w : (l == 2) ? g3w : g4w;

    const int nn = t & 31, kb = t >> 5;
#pragma unroll 4
    for (int pass = 0; pass < 32; ++pass) {
      int kp = pass * 8 + kb;
      int kl = (l == 1) ? kp
                        : 64 * (kp >> 6) + 32 * (kp & 1) + ((kp & 63) >> 1);
      tile[kp][nn] = (_Float16)src[(size_t)kl * 256 + nt * 32 + nn];
    }
    __syncthreads();

    const int lane = t & 63;
    const int nfrag = lane & 31;
    const int kbase = (lane >> 5) * 8;
    _Float16* dst = wtf + ((size_t)(l * 8 + nt) * 16) * 512;
#pragma unroll
    for (int q = 0; q < 4; ++q) {
      int kk = (t >> 6) + 4 * q;
      f16x8 fr;
#pragma unroll
      for (int j = 0; j < 8; ++j)
        fr[j] = tile[kk * 16 + kbase + j][nfrag];
      *(f16x8*)(dst + (size_t)kk * 512 + lane * 8) = fr;
    }
  } else if (blk < 544) {
    // ---- cib = x_i . W0[65:193] + i*W0[193] + b1  (fp32) ----
    float* xs = (float*)&tile[0][0];     // [4][128]
    const int blkc = blk - 32;           // 512 = 32 b x 16 groups
    const int b  = blkc >> 4;
    const int i0 = (blkc & 15) * 4;

#pragma unroll
    for (int u = 0; u < 2; ++u) {
      int idx = u * 256 + t;
      int j = idx >> 7, k = idx & 127;
      xs[j * 128 + k] = x_aux[((size_t)(b * NOBJ + i0 + j)) * 128 + k];
    }
    __syncthreads();

    float c0 = 0.f, c1 = 0.f, c2 = 0.f, c3 = 0.f;
#pragma unroll 8
    for (int k = 0; k < 128; ++k) {
      float w = g1w[(size_t)(65 + k) * 256 + t];
      c0 += xs[k] * w;       c1 += xs[128 + k] * w;
      c2 += xs[256 + k] * w; c3 += xs[384 + k] * w;
    }
    float wc = g1w[(size_t)193 * 256 + t];
    float bb = g1b[t];
    c0 += (float)(i0 + 0) * wc + bb;
    c1 += (float)(i0 + 1) * wc + bb;
    c2 += (float)(i0 + 2) * wc + bb;
    c3 += (float)(i0 + 3) * wc + bb;
    cib[((size_t)(b * NOBJ + i0 + 0)) * 256 + t] = c0;
    cib[((size_t)(b * NOBJ + i0 + 1)) * 256 + t] = c1;
    cib[((size_t)(b * NOBJ + i0 + 2)) * 256 + t] = c2;
    cib[((size_t)(b * NOBJ + i0 + 3)) * 256 + t] = c3;
  } else {
    // ---- h0j = x_j . W0[0:64] + j*W0[64]  (fp32, no bias) ----
    float* xs = (float*)&tile[0][0];     // [8][65]
    const int blk2 = blk - 544;          // 256 = 32 b x 8 jgroups
    const int b  = blk2 >> 3;
    const int j0 = (blk2 & 7) * 8;

#pragma unroll
    for (int u = 0; u < 2; ++u) {
      int idx = u * 256 + t;             // 0..511
      int jj = idx >> 6, k = idx & 63;
      xs[jj * 65 + k] = x_aux[((size_t)(b * NOBJ + j0 + jj)) * 128 + k];
    }
    if (t < 8) xs[t * 65 + 64] = (float)(j0 + t);   // coord j
    __syncthreads();

    float acc[8] = {};
#pragma unroll 5
    for (int k = 0; k < 65; ++k) {
      float w = g1w[(size_t)k * 256 + t];
#pragma unroll
      for (int jj = 0; jj < 8; ++jj) acc[jj] += xs[jj * 65 + k] * w;
    }
#pragma unroll
    for (int jj = 0; jj < 8; ++jj)
      h0j[((size_t)(b * NOBJ + j0 + jj)) * 256 + t] = acc[jj];
  }
}

// ---------------------------------------------------------------------------
// One layer GEMM for a wave: Mt=4 M-tiles x Nt=2 N-groups, 16 k-steps.
// EXPLICIT 1-step double-buffer for A (LDS) and B (L2): fragments for k+1
// are loaded before issuing k's 8 MFMAs, so the compiler's waitcnts carry
// prefetch distance 1 (LDS/L2 latency hidden behind MFMA execution).
// acc[idx = m*2 + ns].
// ---------------------------------------------------------------------------
__device__ __forceinline__ void do_layer16(
    const _Float16* __restrict__ bp0, const _Float16* __restrict__ bp1,
    const _Float16* __restrict__ arow, f32x16 acc[8]) {
  f16x8 a_c[4], a_n[4], b0_c, b1_c, b0_n, b1_n;
#pragma unroll
  for (int m = 0; m < 4; ++m)
    a_c[m] = *(const f16x8*)(arow + (size_t)m * 32 * PADK);
  b0_c = *(const f16x8*)bp0;
  b1_c = *(const f16x8*)bp1;
#pragma unroll
  for (int kk = 0; kk < 16; ++kk) {
    if (kk < 15) {
      b0_n = *(const f16x8*)(bp0 + (size_t)(kk + 1) * 512);
      b1_n = *(const f16x8*)(bp1 + (size_t)(kk + 1) * 512);
#pragma unroll
      for (int m = 0; m < 4; ++m)
        a_n[m] = *(const f16x8*)(arow + (size_t)m * 32 * PADK + (kk + 1) * 16);
    }
#pragma unroll
    for (int m = 0; m < 4; ++m) {
      acc[m * 2]     = MFMA32(a_c[m], b0_c, acc[m * 2]);
      acc[m * 2 + 1] = MFMA32(a_c[m], b1_c, acc[m * 2 + 1]);
    }
    b0_c = b0_n; b1_c = b1_n;
#pragma unroll
    for (int m = 0; m < 4; ++m) a_c[m] = a_n[m];
  }
}

// ---------------------------------------------------------------------------
// Kernel 1: fused g-MLP layers 1-3 + sum-pool for TWO i's per block.
// Block = 256 thr (4 waves). M=128 (2 i's x 64 j), N=256, K=256.
// Tile build: act1[m][n] = relu(h0j[j] + cib[i]) -- coalesced (1 KB row
// per wave instruction), h0j row read once for both i-halves.
// Wave w = nq: Mt=4 x Nt=2 (N-groups 2nq, 2nq+1); dup=1 B (validated).
// ---------------------------------------------------------------------------
__global__ __launch_bounds__(256, 2) void g_mlp_pool(
    const float* __restrict__ h0j,            // [B*64][256] fp32
    const float* __restrict__ cib,            // [B*64][256] fp32
    const _Float16* __restrict__ wtf,         // fragment-ordered
    const float* __restrict__ g2b, const float* __restrict__ g3b,
    const float* __restrict__ g4b,
    float* __restrict__ xg) {                 // [B][256] fp32 (pre-zeroed)
  __shared__ _Float16 As[128][PADK];          // 67.6 KB -> 2 blocks/CU

  const int b  = blockIdx.x >> 5;
  const int i0 = (blockIdx.x & 31) * 2;
  const int t  = threadIdx.x;
  const int lane = t & 63;
  const int wv   = t >> 6;

  // ---- build act1 tile: rows j and 64+j share the same h0j row ----
  {
    const int c = lane * 4;                   // this lane's 4 cols
    const float* hb = h0j + (size_t)(b * NOBJ) * 256 + c;
    const float* c0p = cib + (size_t)(b * NOBJ + i0) * 256 + c;
    f32x4 cv0 = *(const f32x4*)c0p;
    f32x4 cv1 = *(const f32x4*)(c0p + 256);
#pragma unroll
    for (int it = 0; it < 16; ++it) {
      int j = it * 4 + wv;
      f32x4 hv = *(const f32x4*)(hb + (size_t)j * 256);
      f16x4 p0, p1;
#pragma unroll
      for (int q = 0; q < 4; ++q) {
        p0[q] = (_Float16)fmaxf(hv[q] + cv0[q], 0.f);
        p1[q] = (_Float16)fmaxf(hv[q] + cv1[q], 0.f);
      }
      *(f16x4*)&As[j][c]      = p0;
      *(f16x4*)&As[64 + j][c] = p1;
    }
  }
  __syncthreads();

  const int nq   = wv;              // 0..3 -> N-pair (groups 2nq, 2nq+1)
  const int c31  = lane & 31;
  const int h    = lane >> 5;       // 0/1
  const int n0   = nq * 64;
  const float* gb[4] = {nullptr, g2b, g3b, g4b};

  for (int layer = 1; layer < 4; ++layer) {
    const float bv0 = gb[layer][n0 + c31];
    const float bv1 = gb[layer][n0 + 32 + c31];

    f32x16 acc[8];   // [m*2 + ns]
#pragma unroll
    for (int x = 0; x < 8; ++x) acc[x] = (f32x16){};

    const _Float16* bp0 =
        wtf + ((size_t)(layer * 8 + nq * 2) * 16) * 512 + lane * 8;
    const _Float16* bp1 = bp0 + 16 * 512;
    const _Float16* arow = &As[c31][h * 8];

    do_layer16(bp0, bp1, arow, acc);

    if (layer < 3) {
      __syncthreads();   // all waves done reading As
      // C/D layout: col = lane&31, row = (reg&3) + 8*(reg>>2) + 4*h.
      // Pack both N-streams as f16x2 at phys col 64*nq + 2*c.
      // v_cvt_pkrtz packs the pair in one instruction (values >= 0, so
      // RTZ truncation bias is ~0.4 ulp -- negligible vs threshold).
#pragma unroll
      for (int m = 0; m < 4; ++m)
#pragma unroll
        for (int g = 0; g < 4; ++g)
#pragma unroll
          for (int r = 0; r < 4; ++r) {
            const int row = m * 32 + g * 8 + h * 4 + r;
            const int reg = g * 4 + r;
            h16x2 pk = __builtin_amdgcn_cvt_pkrtz(
                fmaxf(acc[m * 2][reg] + bv0, 0.f),
                fmaxf(acc[m * 2 + 1][reg] + bv1, 0.f));
            *(h16x2*)&As[row][n0 + 2 * c31] = pk;
          }
      __syncthreads();
    } else {
      // layer 4: bias + relu + pool over all 128 rows (both i's)
      float s0 = 0.f, s1 = 0.f;
#pragma unroll
      for (int m = 0; m < 4; ++m)
#pragma unroll
        for (int reg = 0; reg < 16; ++reg) {
          s0 += fmaxf(acc[m * 2][reg] + bv0, 0.f);
          s1 += fmaxf(acc[m * 2 + 1][reg] + bv1, 0.f);
        }
      s0 += __shfl_xor(s0, 32, 64);   // combine h=0/h=1 row halves
      s1 += __shfl_xor(s1, 32, 64);
      if (h == 0) {
        atomicAdd(&xg[b * 256 + n0 + c31], s0);
        atomicAdd(&xg[b * 256 + n0 + 32 + c31], s1);
      }
    }
  }
}

// ---------------------------------------------------------------------------
// Kernel 2: f-MLP. One block per batch, 1024 threads: n = t&255 owns column,
// kc = t>>8 owns a 64-wide k-chunk; LDS reduce the 4 partials per column.
// ---------------------------------------------------------------------------
__global__ __launch_bounds__(1024) void f_mlp(
    const float* __restrict__ xg,
    const float* __restrict__ f1w, const float* __restrict__ f1b,
    const float* __restrict__ f2w, const float* __restrict__ f2b,
    const float* __restrict__ f3w, const float* __restrict__ f3b,
    float* __restrict__ out) {
  __shared__ float xs[256], ys[256], ps[4][256];
  const int b = blockIdx.x;
  const int t = threadIdx.x;
  const int n = t & 255;
  const int kc = t >> 8;

  if (t < 256) xs[t] = xg[b * 256 + t];
  __syncthreads();

  float p = 0.f;
#pragma unroll 8
  for (int k0 = 0; k0 < 64; ++k0) {
    int k = kc * 64 + k0;
    p += xs[k] * f1w[k * 256 + n];
  }
  ps[kc][n] = p;
  __syncthreads();
  if (t < 256)
    ys[t] = fmaxf(f1b[t] + ps[0][t] + ps[1][t] + ps[2][t] + ps[3][t], 0.f);
  __syncthreads();

  p = 0.f;
#pragma unroll 8
  for (int k0 = 0; k0 < 64; ++k0) {
    int k = kc * 64 + k0;
    p += ys[k] * f2w[k * 256 + n];
  }
  ps[kc][n] = p;
  __syncthreads();
  if (t < 256)
    xs[t] = fmaxf(f2b[t] + ps[0][t] + ps[1][t] + ps[2][t] + ps[3][t], 0.f);
  __syncthreads();

  p = 0.f;
#pragma unroll 8
  for (int k0 = 0; k0 < 64; ++k0) {
    int k = kc * 64 + k0;
    p += xs[k] * f3w[k * 256 + n];
  }
  ps[kc][n] = p;
  __syncthreads();
  if (t < 256)
    out[b * 256 + t] = f3b[t] + ps[0][t] + ps[1][t] + ps[2][t] + ps[3][t];
}

// ---------------------------------------------------------------------------
extern "C" void kernel_launch(void* const* d_in, const int* in_sizes, int n_in,
                              void* d_out, int out_size, void* d_ws, size_t ws_size,
                              hipStream_t stream) {
  const float* x_aux = (const float*)d_in[0];
  const float* g1w = (const float*)d_in[1];
  const float* g1b = (const float*)d_in[2];
  const float* g2w = (const float*)d_in[3];
  const float* g2b = (const float*)d_in[4];
  const float* g3w = (const float*)d_in[5];
  const float* g3b = (const float*)d_in[6];
  const float* g4w = (const float*)d_in[7];
  const float* g4b = (const float*)d_in[8];
  const float* f1w = (const float*)d_in[9];
  const float* f1b = (const float*)d_in[10];
  const float* f2w = (const float*)d_in[11];
  const float* f2b = (const float*)d_in[12];
  const float* f3w = (const float*)d_in[13];
  const float* f3b = (const float*)d_in[14];
  float* out = (float*)d_out;

  _Float16* wtf = (_Float16*)d_ws;                                  // 512 KB
  float* xg  = (float*)((char*)d_ws + 512u * 1024u);                // 32 KB
  float* cib = (float*)((char*)d_ws + 544u * 1024u);                // 2 MB
  float* h0j = (float*)((char*)d_ws + 544u * 1024u + 2048u * 1024u);// 2 MB

  hipLaunchKernelGGL(prep_all, dim3(800), dim3(256), 0, stream,
                     x_aux, g1w, g1b, g2w, g3w, g4w, wtf, xg, cib, h0j);
  hipLaunchKernelGGL(g_mlp_pool, dim3(BATCH * 32), dim3(256), 0, stream,
                     h0j, cib, wtf, g2b, g3b, g4b, xg);
  hipLaunchKernelGGL(f_mlp, dim3(BATCH), dim3(1024), 0, stream,
                     xg, f1w, f1b, f2w, f2b, f3w, f3b, out);
}

// Round 14
// 146.893 us; speedup vs baseline: 1.3706x; 1.0004x over previous
//
#include <hip/hip_runtime.h>

#define BATCH 32
#define NOBJ  64
#define PADK  264   // halfs; A-tile row stride 528 B (16B-aligned)

typedef _Float16 f16x2 __attribute__((ext_vector_type(2)));
typedef __fp16   h16x2 __attribute__((ext_vector_type(2)));
typedef _Float16 f16x4 __attribute__((ext_vector_type(4)));
typedef _Float16 f16x8 __attribute__((ext_vector_type(8)));
typedef float    f32x4 __attribute__((ext_vector_type(4)));
typedef float    f32x16 __attribute__((ext_vector_type(16)));

#define MFMA32(a, b, c) __builtin_amdgcn_mfma_f32_32x32x16_f16((a), (b), (c), 0, 0, 0)

// ---------------------------------------------------------------------------
// Layer-0 is removed from the MFMA loop entirely (exact algebra):
//   h1[b][(i,j)][n] = relu( h0j[b][j][n] + cib[b][i][n] )
//   h0j = x_j·W0[0:64] + j·W0[64]          (per-batch, shared by all i)
//   cib = x_i·W0[65:193] + i·W0[193] + b1  (per-(b,i))
// Both fp32, computed in prep_all. g_mlp builds act1 directly and runs
// layers 1-3 (K=256, 16 steps each).
//
// Activation LDS layout after layer-1/2 epilogues: physical col
// p = 64*nq + 2*c + ns holds logical col n = 64*nq + 32*ns + c (f16x2 pack).
// Layer-2/3 weight k-order: klog(p) = 64*(p>>6) + 32*(p&1) + ((p&63)>>1).
// Layer-1 weights use identity k-order (act1 is built in plain layout).
//
// Dispatches (3): prep_all (800 blocks), g_mlp_pool (1024), f_mlp (32).
// NO device-scope fences anywhere (r10 lesson: __threadfence = L2 flush).
// do_layer16 = r11 simple form (r13's explicit dbuf regressed: m131-m141
// precedent — compiler scheduling already optimal for this structure).
// ---------------------------------------------------------------------------

// ---------------------------------------------------------------------------
// Kernel 0: prep_all.
// blk 0..31  : zero xg; repack weights l=blk>>3 in MFMA B-fragment order
//              (skip l==0 -- unused):
//              wtf[l][ngrp=8][kk=16][lane=64][j=8] = W_l[klog][nlog]
//              nlog = ngrp*32+(lane&31), kphys = kk*16+(lane>>5)*8+j
//              l==1: klog = kphys; l>=2: 2-col interleave mapping.
// blk 32..543: cib (per-(b, 4 i's)); thread t = col n.
// blk 544..799: h0j (per-(b, 8 j's)); thread t = col n.
// ---------------------------------------------------------------------------
__global__ __launch_bounds__(256) void prep_all(
    const float* __restrict__ x_aux,
    const float* __restrict__ g1w, const float* __restrict__ g1b,
    const float* __restrict__ g2w, const float* __restrict__ g3w,
    const float* __restrict__ g4w,
    _Float16* __restrict__ wtf, float* __restrict__ xg,
    float* __restrict__ cib, float* __restrict__ h0j) {
  __shared__ _Float16 tile[256][33];
  const int blk = blockIdx.x;
  const int t = threadIdx.x;

  if (blk < 32) {
    xg[blk * 256 + t] = 0.0f;
    const int l = blk >> 3;
    if (l == 0) return;                 // layer-0 weights not needed
    const int nt = blk & 7;
    const float* src = (l == 1) ? g2w : (l == 2) ? g3w : g4w;

    const int nn = t & 31, kb = t >> 5;
#pragma unroll 4
    for (int pass = 0; pass < 32; ++pass) {
      int kp = pass * 8 + kb;
      int kl = (l == 1) ? kp
                        : 64 * (kp >> 6) + 32 * (kp & 1) + ((kp & 63) >> 1);
      tile[kp][nn] = (_Float16)src[(size_t)kl * 256 + nt * 32 + nn];
    }
    __syncthreads();

    const int lane = t & 63;
    const int nfrag = lane & 31;
    const int kbase = (lane >> 5) * 8;
    _Float16* dst = wtf + ((size_t)(l * 8 + nt) * 16) * 512;
#pragma unroll
    for (int q = 0; q < 4; ++q) {
      int kk = (t >> 6) + 4 * q;
      f16x8 fr;
#pragma unroll
      for (int j = 0; j < 8; ++j)
        fr[j] = tile[kk * 16 + kbase + j][nfrag];
      *(f16x8*)(dst + (size_t)kk * 512 + lane * 8) = fr;
    }
  } else if (blk < 544) {
    // ---- cib = x_i . W0[65:193] + i*W0[193] + b1  (fp32) ----
    float* xs = (float*)&tile[0][0];     // [4][128]
    const int blkc = blk - 32;           // 512 = 32 b x 16 groups
    const int b  = blkc >> 4;
    const int i0 = (blkc & 15) * 4;

#pragma unroll
    for (int u = 0; u < 2; ++u) {
      int idx = u * 256 + t;
      int j = idx >> 7, k = idx & 127;
      xs[j * 128 + k] = x_aux[((size_t)(b * NOBJ + i0 + j)) * 128 + k];
    }
    __syncthreads();

    float c0 = 0.f, c1 = 0.f, c2 = 0.f, c3 = 0.f;
#pragma unroll 8
    for (int k = 0; k < 128; ++k) {
      float w = g1w[(size_t)(65 + k) * 256 + t];
      c0 += xs[k] * w;       c1 += xs[128 + k] * w;
      c2 += xs[256 + k] * w; c3 += xs[384 + k] * w;
    }
    float wc = g1w[(size_t)193 * 256 + t];
    float bb = g1b[t];
    c0 += (float)(i0 + 0) * wc + bb;
    c1 += (float)(i0 + 1) * wc + bb;
    c2 += (float)(i0 + 2) * wc + bb;
    c3 += (float)(i0 + 3) * wc + bb;
    cib[((size_t)(b * NOBJ + i0 + 0)) * 256 + t] = c0;
    cib[((size_t)(b * NOBJ + i0 + 1)) * 256 + t] = c1;
    cib[((size_t)(b * NOBJ + i0 + 2)) * 256 + t] = c2;
    cib[((size_t)(b * NOBJ + i0 + 3)) * 256 + t] = c3;
  } else {
    // ---- h0j = x_j . W0[0:64] + j*W0[64]  (fp32, no bias) ----
    float* xs = (float*)&tile[0][0];     // [8][65]
    const int blk2 = blk - 544;          // 256 = 32 b x 8 jgroups
    const int b  = blk2 >> 3;
    const int j0 = (blk2 & 7) * 8;

#pragma unroll
    for (int u = 0; u < 2; ++u) {
      int idx = u * 256 + t;             // 0..511
      int jj = idx >> 6, k = idx & 63;
      xs[jj * 65 + k] = x_aux[((size_t)(b * NOBJ + j0 + jj)) * 128 + k];
    }
    if (t < 8) xs[t * 65 + 64] = (float)(j0 + t);   // coord j
    __syncthreads();

    float acc[8] = {};
#pragma unroll 5
    for (int k = 0; k < 65; ++k) {
      float w = g1w[(size_t)k * 256 + t];
#pragma unroll
      for (int jj = 0; jj < 8; ++jj) acc[jj] += xs[jj * 65 + k] * w;
    }
#pragma unroll
    for (int jj = 0; jj < 8; ++jj)
      h0j[((size_t)(b * NOBJ + j0 + jj)) * 256 + t] = acc[jj];
  }
}

// ---------------------------------------------------------------------------
// One layer GEMM for a wave: Mt=4 M-tiles x Nt=2 N-groups, 16 k-steps.
// Simple in-loop loads (r11 form, measured best) -- compiler schedules
// lgkmcnt/vmcnt with its own prefetch distance; explicit dbuf regressed.
// acc[idx = m*2 + ns].
// ---------------------------------------------------------------------------
__device__ __forceinline__ void do_layer16(
    const _Float16* __restrict__ bp0, const _Float16* __restrict__ bp1,
    const _Float16* __restrict__ arow, f32x16 acc[8]) {
#pragma unroll
  for (int kk = 0; kk < 16; ++kk) {
    f16x8 b0 = *(const f16x8*)(bp0 + (size_t)kk * 512);
    f16x8 b1 = *(const f16x8*)(bp1 + (size_t)kk * 512);
#pragma unroll
    for (int m = 0; m < 4; ++m) {
      f16x8 a = *(const f16x8*)(arow + (size_t)m * 32 * PADK + kk * 16);
      acc[m * 2]     = MFMA32(a, b0, acc[m * 2]);
      acc[m * 2 + 1] = MFMA32(a, b1, acc[m * 2 + 1]);
    }
  }
}

// ---------------------------------------------------------------------------
// Kernel 1: fused g-MLP layers 1-3 + sum-pool for TWO i's per block.
// Block = 256 thr (4 waves). M=128 (2 i's x 64 j), N=256, K=256.
// Tile build: act1[m][n] = relu(h0j[j] + cib[i]) -- coalesced (1 KB row
// per wave instruction), h0j row read once for both i-halves.
// Wave w = nq: Mt=4 x Nt=2 (N-groups 2nq, 2nq+1); dup=1 B (validated).
// ---------------------------------------------------------------------------
__global__ __launch_bounds__(256, 2) void g_mlp_pool(
    const float* __restrict__ h0j,            // [B*64][256] fp32
    const float* __restrict__ cib,            // [B*64][256] fp32
    const _Float16* __restrict__ wtf,         // fragment-ordered
    const float* __restrict__ g2b, const float* __restrict__ g3b,
    const float* __restrict__ g4b,
    float* __restrict__ xg) {                 // [B][256] fp32 (pre-zeroed)
  __shared__ _Float16 As[128][PADK];          // 67.6 KB -> 2 blocks/CU

  const int b  = blockIdx.x >> 5;
  const int i0 = (blockIdx.x & 31) * 2;
  const int t  = threadIdx.x;
  const int lane = t & 63;
  const int wv   = t >> 6;

  // ---- build act1 tile: rows j and 64+j share the same h0j row ----
  {
    const int c = lane * 4;                   // this lane's 4 cols
    const float* hb = h0j + (size_t)(b * NOBJ) * 256 + c;
    const float* c0p = cib + (size_t)(b * NOBJ + i0) * 256 + c;
    f32x4 cv0 = *(const f32x4*)c0p;
    f32x4 cv1 = *(const f32x4*)(c0p + 256);
#pragma unroll
    for (int it = 0; it < 16; ++it) {
      int j = it * 4 + wv;
      f32x4 hv = *(const f32x4*)(hb + (size_t)j * 256);
      f16x4 p0, p1;
#pragma unroll
      for (int q = 0; q < 4; ++q) {
        p0[q] = (_Float16)fmaxf(hv[q] + cv0[q], 0.f);
        p1[q] = (_Float16)fmaxf(hv[q] + cv1[q], 0.f);
      }
      *(f16x4*)&As[j][c]      = p0;
      *(f16x4*)&As[64 + j][c] = p1;
    }
  }
  __syncthreads();

  const int nq   = wv;              // 0..3 -> N-pair (groups 2nq, 2nq+1)
  const int c31  = lane & 31;
  const int h    = lane >> 5;       // 0/1
  const int n0   = nq * 64;
  const float* gb[4] = {nullptr, g2b, g3b, g4b};

  for (int layer = 1; layer < 4; ++layer) {
    const float bv0 = gb[layer][n0 + c31];
    const float bv1 = gb[layer][n0 + 32 + c31];

    f32x16 acc[8];   // [m*2 + ns]
#pragma unroll
    for (int x = 0; x < 8; ++x) acc[x] = (f32x16){};

    const _Float16* bp0 =
        wtf + ((size_t)(layer * 8 + nq * 2) * 16) * 512 + lane * 8;
    const _Float16* bp1 = bp0 + 16 * 512;
    const _Float16* arow = &As[c31][h * 8];

    do_layer16(bp0, bp1, arow, acc);

    if (layer < 3) {
      __syncthreads();   // all waves done reading As
      // C/D layout: col = lane&31, row = (reg&3) + 8*(reg>>2) + 4*h.
      // Pack both N-streams as f16x2 at phys col 64*nq + 2*c.
      // v_cvt_pkrtz packs in one instruction (values >= 0, RTZ bias ~0).
#pragma unroll
      for (int m = 0; m < 4; ++m)
#pragma unroll
        for (int g = 0; g < 4; ++g)
#pragma unroll
          for (int r = 0; r < 4; ++r) {
            const int row = m * 32 + g * 8 + h * 4 + r;
            const int reg = g * 4 + r;
            h16x2 pk = __builtin_amdgcn_cvt_pkrtz(
                fmaxf(acc[m * 2][reg] + bv0, 0.f),
                fmaxf(acc[m * 2 + 1][reg] + bv1, 0.f));
            *(h16x2*)&As[row][n0 + 2 * c31] = pk;
          }
      __syncthreads();
    } else {
      // layer 4: bias + relu + pool over all 128 rows (both i's)
      float s0 = 0.f, s1 = 0.f;
#pragma unroll
      for (int m = 0; m < 4; ++m)
#pragma unroll
        for (int reg = 0; reg < 16; ++reg) {
          s0 += fmaxf(acc[m * 2][reg] + bv0, 0.f);
          s1 += fmaxf(acc[m * 2 + 1][reg] + bv1, 0.f);
        }
      s0 += __shfl_xor(s0, 32, 64);   // combine h=0/h=1 row halves
      s1 += __shfl_xor(s1, 32, 64);
      if (h == 0) {
        atomicAdd(&xg[b * 256 + n0 + c31], s0);
        atomicAdd(&xg[b * 256 + n0 + 32 + c31], s1);
      }
    }
  }
}

// ---------------------------------------------------------------------------
// Kernel 2: f-MLP. One block per batch, 1024 threads: n = t&255 owns column,
// kc = t>>8 owns a 64-wide k-chunk; LDS reduce the 4 partials per column.
// ---------------------------------------------------------------------------
__global__ __launch_bounds__(1024) void f_mlp(
    const float* __restrict__ xg,
    const float* __restrict__ f1w, const float* __restrict__ f1b,
    const float* __restrict__ f2w, const float* __restrict__ f2b,
    const float* __restrict__ f3w, const float* __restrict__ f3b,
    float* __restrict__ out) {
  __shared__ float xs[256], ys[256], ps[4][256];
  const int b = blockIdx.x;
  const int t = threadIdx.x;
  const int n = t & 255;
  const int kc = t >> 8;

  if (t < 256) xs[t] = xg[b * 256 + t];
  __syncthreads();

  float p = 0.f;
#pragma unroll 8
  for (int k0 = 0; k0 < 64; ++k0) {
    int k = kc * 64 + k0;
    p += xs[k] * f1w[k * 256 + n];
  }
  ps[kc][n] = p;
  __syncthreads();
  if (t < 256)
    ys[t] = fmaxf(f1b[t] + ps[0][t] + ps[1][t] + ps[2][t] + ps[3][t], 0.f);
  __syncthreads();

  p = 0.f;
#pragma unroll 8
  for (int k0 = 0; k0 < 64; ++k0) {
    int k = kc * 64 + k0;
    p += ys[k] * f2w[k * 256 + n];
  }
  ps[kc][n] = p;
  __syncthreads();
  if (t < 256)
    xs[t] = fmaxf(f2b[t] + ps[0][t] + ps[1][t] + ps[2][t] + ps[3][t], 0.f);
  __syncthreads();

  p = 0.f;
#pragma unroll 8
  for (int k0 = 0; k0 < 64; ++k0) {
    int k = kc * 64 + k0;
    p += xs[k] * f3w[k * 256 + n];
  }
  ps[kc][n] = p;
  __syncthreads();
  if (t < 256)
    out[b * 256 + t] = f3b[t] + ps[0][t] + ps[1][t] + ps[2][t] + ps[3][t];
}

// ---------------------------------------------------------------------------
extern "C" void kernel_launch(void* const* d_in, const int* in_sizes, int n_in,
                              void* d_out, int out_size, void* d_ws, size_t ws_size,
                              hipStream_t stream) {
  const float* x_aux = (const float*)d_in[0];
  const float* g1w = (const float*)d_in[1];
  const float* g1b = (const float*)d_in[2];
  const float* g2w = (const float*)d_in[3];
  const float* g2b = (const float*)d_in[4];
  const float* g3w = (const float*)d_in[5];
  const float* g3b = (const float*)d_in[6];
  const float* g4w = (const float*)d_in[7];
  const float* g4b = (const float*)d_in[8];
  const float* f1w = (const float*)d_in[9];
  const float* f1b = (const float*)d_in[10];
  const float* f2w = (const float*)d_in[11];
  const float* f2b = (const float*)d_in[12];
  const float* f3w = (const float*)d_in[13];
  const float* f3b = (const float*)d_in[14];
  float* out = (float*)d_out;

  _Float16* wtf = (_Float16*)d_ws;                                  // 512 KB
  float* xg  = (float*)((char*)d_ws + 512u * 1024u);                // 32 KB
  float* cib = (float*)((char*)d_ws + 544u * 1024u);                // 2 MB
  float* h0j = (float*)((char*)d_ws + 544u * 1024u + 2048u * 1024u);// 2 MB

  hipLaunchKernelGGL(prep_all, dim3(800), dim3(256), 0, stream,
                     x_aux, g1w, g1b, g2w, g3w, g4w, wtf, xg, cib, h0j);
  hipLaunchKernelGGL(g_mlp_pool, dim3(BATCH * 32), dim3(256), 0, stream,
                     h0j, cib, wtf, g2b, g3b, g4b, xg);
  hipLaunchKernelGGL(f_mlp, dim3(BATCH), dim3(1024), 0, stream,
                     xg, f1w, f1b, f2w, f2b, f3w, f3b, out);
}